// Round 20
// baseline (521.701 us; speedup 1.0000x reference)
//
#include <hip/hip_runtime.h>

#define NN 200000
#define CC 2000
#define EBN 2000000
#define ESN 40000
#define EPSA 1e-4f
#define SCH 8000
#define NBKT 1563
#define CVB 1056
#define HSB 977

typedef unsigned short ushort_t;
typedef float f32x4 __attribute__((ext_vector_type(4)));
typedef __bf16 bf16x8 __attribute__((ext_vector_type(8)));
typedef _Float16 f16x8 __attribute__((ext_vector_type(8)));

__device__ __forceinline__ unsigned fenc(float f) {
    unsigned b = __float_as_uint(f);
    return (b & 0x80000000u) ? ~b : (b | 0x80000000u);
}
__device__ __forceinline__ float fdec(unsigned u) {
    return (u & 0x80000000u) ? __uint_as_float(u ^ 0x80000000u) : __uint_as_float(~u);
}
__device__ __forceinline__ unsigned f2bf(float f) {  // RNE f32 -> bf16 bits
    unsigned u = __float_as_uint(f);
    return (u + 0x7fffu + ((u >> 16) & 1u)) >> 16;
}
__device__ __forceinline__ float bf2f(ushort_t u) { return __uint_as_float(((unsigned)u) << 16); }
__device__ __forceinline__ ushort_t f2h(float f) {
    const _Float16 h = (_Float16)f;
    return __builtin_bit_cast(ushort_t, h);
}
__device__ __forceinline__ float dot16(const ushort_t* __restrict__ emb_h, const float* __restrict__ means,
                                       int s, int d) {
    const uint4 e0v = *(const uint4*)(emb_h + (size_t)s * 16);
    const uint4 e1v = *(const uint4*)(emb_h + (size_t)s * 16 + 8);
    const float4* mv = (const float4*)(means + (size_t)d * 16);
    const float4 m0 = mv[0], m1 = mv[1], m2 = mv[2], m3 = mv[3];
    float dot = 0.f;
    dot += bf2f((ushort_t)(e0v.x & 0xFFFF)) * m0.x + bf2f((ushort_t)(e0v.x >> 16)) * m0.y;
    dot += bf2f((ushort_t)(e0v.y & 0xFFFF)) * m0.z + bf2f((ushort_t)(e0v.y >> 16)) * m0.w;
    dot += bf2f((ushort_t)(e0v.z & 0xFFFF)) * m1.x + bf2f((ushort_t)(e0v.z >> 16)) * m1.y;
    dot += bf2f((ushort_t)(e0v.w & 0xFFFF)) * m1.z + bf2f((ushort_t)(e0v.w >> 16)) * m1.w;
    dot += bf2f((ushort_t)(e1v.x & 0xFFFF)) * m2.x + bf2f((ushort_t)(e1v.x >> 16)) * m2.y;
    dot += bf2f((ushort_t)(e1v.y & 0xFFFF)) * m2.z + bf2f((ushort_t)(e1v.y >> 16)) * m2.w;
    dot += bf2f((ushort_t)(e1v.z & 0xFFFF)) * m3.x + bf2f((ushort_t)(e1v.z >> 16)) * m3.y;
    dot += bf2f((ushort_t)(e1v.w & 0xFFFF)) * m3.z + bf2f((ushort_t)(e1v.w >> 16)) * m3.w;
    return dot;
}

// ---- fused setup: weight convert (blocks 0..CVB-1) + triple histogram (blocks CVB..) ----
__global__ __launch_bounds__(256) void k_setup(const float* __restrict__ cW1, const float* __restrict__ cW2,
                                               const float* __restrict__ eW1, const float* __restrict__ eW2,
                                               ushort_t* __restrict__ cW1h, ushort_t* __restrict__ cW2h,
                                               ushort_t* __restrict__ eW1t, ushort_t* __restrict__ eW2t,
                                               const int* __restrict__ bsrc, const int* __restrict__ bdst,
                                               const int* __restrict__ clusters,
                                               int* __restrict__ hist_d, int* __restrict__ hist_s,
                                               int* __restrict__ hist_c) {
    __shared__ int hd[CC];
    __shared__ int hs[NBKT];
    __shared__ int hc[CC];
    if (blockIdx.x < CVB) {
        int id = blockIdx.x * 256 + threadIdx.x;
        if (id < 65536) {
            const int n = id >> 7, k = id & 127;
            cW1h[id] = f2h(cW1[k * 512 + n]);
            return;
        }
        id -= 65536;
        if (id < 8192) {
            const int n = id >> 9, k = id & 511;
            cW2h[id] = f2h(cW2[k * 16 + n]);
            return;
        }
        id -= 8192;
        if (id < 131072) { const int n = id >> 8, k = id & 255; eW1t[id] = (ushort_t)f2bf(eW1[k * 512 + n]); return; }
        id -= 131072;
        if (id < 65536) { const int n = id >> 9, k = id & 511; eW2t[id] = (ushort_t)f2bf(eW2[k * 128 + n]); return; }
        return;
    }
    const int t = threadIdx.x;
    for (int i = t; i < CC; i += 256) { hd[i] = 0; hc[i] = 0; }
    for (int i = t; i < NBKT; i += 256) hs[i] = 0;
    __syncthreads();
    for (int e = (blockIdx.x - CVB) * 256 + t; e < EBN; e += HSB * 256) {
        atomicAdd(&hd[bdst[e]], 1);
        atomicAdd(&hs[bsrc[e] >> 7], 1);
    }
    for (int nidx = (blockIdx.x - CVB) * 256 + t; nidx < NN; nidx += HSB * 256) {
        const int cl = clusters[nidx];
        if ((unsigned)cl < CC) atomicAdd(&hc[cl], 1);
    }
    __syncthreads();
    for (int i = t; i < CC; i += 256) {
        if (hd[i]) atomicAdd(&hist_d[i], hd[i]);
        if (hc[i]) atomicAdd(&hist_c[i], hc[i]);
    }
    for (int i = t; i < NBKT; i += 256) if (hs[i]) atomicAdd(&hist_s[i], hs[i]);
}

// ---------------- triple exclusive scan ----------------
__global__ __launch_bounds__(1024) void k_scan3(const int* __restrict__ hist_d, int* __restrict__ offs_d,
                                                int* __restrict__ cursor_d, const int* __restrict__ hist_s,
                                                int* __restrict__ offs_s, int* __restrict__ cursor_s,
                                                const int* __restrict__ hist_c, int* __restrict__ offs_c,
                                                int* __restrict__ cursor_c) {
    const int* hist = (blockIdx.x == 0) ? hist_d : (blockIdx.x == 1) ? hist_s : hist_c;
    int* offs = (blockIdx.x == 0) ? offs_d : (blockIdx.x == 1) ? offs_s : offs_c;
    int* cursor = (blockIdx.x == 0) ? cursor_d : (blockIdx.x == 1) ? cursor_s : cursor_c;
    const int n = (blockIdx.x == 1) ? NBKT : CC;
    __shared__ int buf[2][2048];
    const int t = threadIdx.x;
    buf[0][t]        = (t        < n) ? hist[t]        : 0;
    buf[0][t + 1024] = (t + 1024 < n) ? hist[t + 1024] : 0;
    __syncthreads();
    int pp = 0;
    for (int off = 1; off < 2048; off <<= 1) {
        const int np = pp ^ 1;
        for (int i = t; i < 2048; i += 1024) {
            int v = buf[pp][i];
            if (i >= off) v += buf[pp][i - off];
            buf[np][i] = v;
        }
        pp = np;
        __syncthreads();
    }
    for (int i = t; i < n; i += 1024) {
        const int ex = (i == 0) ? 0 : buf[pp][i - 1];
        offs[i] = ex;
        cursor[i] = ex;
    }
}

// ---------------- node counting-sort by cluster ----------------
__global__ __launch_bounds__(512) void k_nsort(const int* __restrict__ clusters, int* __restrict__ cursor_c,
                                               int* __restrict__ nid_sorted) {
    __shared__ int h[CC];
    __shared__ int base[CC];
    const int t = threadIdx.x;
    const int n0 = blockIdx.x * 8000;
    for (int i = t; i < CC; i += 512) h[i] = 0;
    __syncthreads();
    for (int i = t; i < 8000; i += 512) {
        const int cl = clusters[n0 + i];
        if ((unsigned)cl < CC) atomicAdd(&h[cl], 1);
    }
    __syncthreads();
    for (int i = t; i < CC; i += 512) {
        const int c = h[i];
        if (c) base[i] = atomicAdd(&cursor_c[i], c);
        h[i] = 0;
    }
    __syncthreads();
    for (int i = t; i < 8000; i += 512) {
        const int cl = clusters[n0 + i];
        if ((unsigned)cl < CC) {
            const int r = atomicAdd(&h[cl], 1);
            nid_sorted[base[cl] + r] = n0 + i;
        }
    }
}

// ---------------- node MLP: single-fp16 MFMA both phases, no global atomics ----------------
__global__ __launch_bounds__(256, 3) void k_mlp1(
    const float* __restrict__ nodes,
    const ushort_t* __restrict__ W1h, const float* __restrict__ b1,
    const float* __restrict__ g1, const float* __restrict__ be1,
    const ushort_t* __restrict__ W2h, const float* __restrict__ b2,
    ushort_t* __restrict__ emb_h, float* __restrict__ emb_f, ushort_t* __restrict__ nodes_h) {
    __shared__ char Ubuf[16384];
    __shared__ float redS[4][32], redQ[4][32];
    ushort_t* Xh = (ushort_t*)Ubuf;
    const int tid = threadIdx.x;
    const int row0 = blockIdx.x * 32;

#pragma unroll
    for (int i = 0; i < 2; ++i) {
        const int c = tid + 256 * i;
        const int row = c >> 4, c8 = c & 15;
        const float4* gp = (const float4*)(nodes + (size_t)(row0 + row) * 128 + c8 * 8);
        const float4 u = gp[0], v = gp[1];
        uint4 pkh;
        pkh.x = f2h(u.x) | ((unsigned)f2h(u.y) << 16);
        pkh.y = f2h(u.z) | ((unsigned)f2h(u.w) << 16);
        pkh.z = f2h(v.x) | ((unsigned)f2h(v.y) << 16);
        pkh.w = f2h(v.z) | ((unsigned)f2h(v.w) << 16);
        const int byte = row * 256 + ((c8 * 16) ^ ((row & 7) << 4));
        *(uint4*)((char*)Xh + byte) = pkh;
        if (nodes_h) {
            uint4 pkb;
            pkb.x = f2bf(u.x) | (f2bf(u.y) << 16);
            pkb.y = f2bf(u.z) | (f2bf(u.w) << 16);
            pkb.z = f2bf(v.x) | (f2bf(v.y) << 16);
            pkb.w = f2bf(v.z) | (f2bf(v.w) << 16);
            ((uint4*)nodes_h)[(size_t)(row0 + row) * 16 + c8] = pkb;
        }
    }
    __syncthreads();

    const int wv = tid >> 6, l = tid & 63;
    const int q = l >> 4, c16 = l & 15;
    const int wcol0 = wv * 128;

    f32x4 acc[2][8];
#pragma unroll
    for (int mt = 0; mt < 2; ++mt)
#pragma unroll
        for (int nt = 0; nt < 8; ++nt) acc[mt][nt] = (f32x4){0.f, 0.f, 0.f, 0.f};

#pragma unroll
    for (int ks = 0; ks < 4; ++ks) {
        f16x8 ah[2];
#pragma unroll
        for (int mt = 0; mt < 2; ++mt) {
            const int row = 16 * mt + c16;
            const int byte = row * 256 + ((64 * ks + 16 * q) ^ ((row & 7) << 4));
            ah[mt] = __builtin_bit_cast(f16x8, *(const uint4*)((const char*)Xh + byte));
        }
#pragma unroll
        for (int nt = 0; nt < 8; ++nt) {
            const int n = wcol0 + 16 * nt + c16;
            const f16x8 bh = __builtin_bit_cast(f16x8, *(const uint4*)(W1h + n * 128 + 32 * ks + 8 * q));
#pragma unroll
            for (int mt = 0; mt < 2; ++mt)
                acc[mt][nt] = __builtin_amdgcn_mfma_f32_16x16x32_f16(ah[mt], bh, acc[mt][nt], 0, 0, 0);
        }
    }

    float b1v[8], g1v[8], bev[8];
#pragma unroll
    for (int nt = 0; nt < 8; ++nt) {
        const int col = wcol0 + 16 * nt + c16;
        b1v[nt] = b1[col]; g1v[nt] = g1[col]; bev[nt] = be1[col];
    }
    float sS[2][4], sQ[2][4];
#pragma unroll
    for (int mt = 0; mt < 2; ++mt)
#pragma unroll
        for (int r = 0; r < 4; ++r) {
            float s = 0.f, qq = 0.f;
#pragma unroll
            for (int nt = 0; nt < 8; ++nt) {
                const float h = acc[mt][nt][r] + b1v[nt];
                acc[mt][nt][r] = h;
                s += h; qq += h * h;
            }
#pragma unroll
            for (int off = 1; off < 16; off <<= 1) {
                s += __shfl_xor(s, off);
                qq += __shfl_xor(qq, off);
            }
            sS[mt][r] = s; sQ[mt][r] = qq;
        }
    if (c16 == 0) {
#pragma unroll
        for (int mt = 0; mt < 2; ++mt)
#pragma unroll
            for (int r = 0; r < 4; ++r) {
                const int row = 16 * mt + 4 * q + r;
                redS[wv][row] = sS[mt][r];
                redQ[wv][row] = sQ[mt][r];
            }
    }
    __syncthreads();

    float mean[2][4], inv[2][4];
#pragma unroll
    for (int mt = 0; mt < 2; ++mt)
#pragma unroll
        for (int r = 0; r < 4; ++r) {
            const int row = 16 * mt + 4 * q + r;
            const float S = redS[0][row] + redS[1][row] + redS[2][row] + redS[3][row];
            const float Q = redQ[0][row] + redQ[1][row] + redQ[2][row] + redQ[3][row];
            const float m_ = S * (1.f / 512.f);
            mean[mt][r] = m_;
            inv[mt][r] = rsqrtf(Q * (1.f / 512.f) - m_ * m_ + 1e-5f);
        }

    ushort_t* Hw = (ushort_t*)(Ubuf + 8192 + wv * 2048);
    f32x4 acc2[2];
    acc2[0] = (f32x4){0.f, 0.f, 0.f, 0.f};
    acc2[1] = (f32x4){0.f, 0.f, 0.f, 0.f};
#pragma unroll
    for (int ch = 0; ch < 4; ++ch) {
#pragma unroll
        for (int mt = 0; mt < 2; ++mt)
#pragma unroll
            for (int r = 0; r < 4; ++r) {
                const int row = 16 * mt + 4 * q + r;
                const int swz = (((row >> 2) & 1) << 3) | (((row >> 3) & 1) << 4);
#pragma unroll
                for (int ntl = 0; ntl < 2; ++ntl) {
                    const int nt = 2 * ch + ntl;
                    const float rv = fmaxf((acc[mt][nt][r] - mean[mt][r]) * inv[mt][r] * g1v[nt] + bev[nt], 0.f);
                    Hw[row * 32 + ((16 * ntl + c16) ^ swz)] = f2h(rv);
                }
            }
        const int kg = wcol0 + 32 * ch + 8 * q;
        const f16x8 bh = __builtin_bit_cast(f16x8, *(const uint4*)(W2h + c16 * 512 + kg));
#pragma unroll
        for (int mt = 0; mt < 2; ++mt) {
            const int row = 16 * mt + c16;
            const int swz = (((row >> 2) & 1) << 3) | (((row >> 3) & 1) << 4);
            const int ci = (8 * q) ^ swz;
            const f16x8 ah = __builtin_bit_cast(f16x8, *(const uint4*)(Hw + row * 32 + ci));
            acc2[mt] = __builtin_amdgcn_mfma_f32_16x16x32_f16(ah, bh, acc2[mt], 0, 0, 0);
        }
    }
    __syncthreads();

    float* Cb = (float*)Ubuf;  // [4][32][16] = 8 KB
#pragma unroll
    for (int mt = 0; mt < 2; ++mt)
#pragma unroll
        for (int r = 0; r < 4; ++r) Cb[(wv * 32 + 16 * mt + 4 * q + r) * 16 + c16] = acc2[mt][r];
    __syncthreads();

#pragma unroll
    for (int rep = 0; rep < 2; ++rep) {
        const int slot = tid + 256 * rep;
        const int row = slot >> 4, col = slot & 15;
        float val = Cb[(0 * 32 + row) * 16 + col] + Cb[(1 * 32 + row) * 16 + col] +
                    Cb[(2 * 32 + row) * 16 + col] + Cb[(3 * 32 + row) * 16 + col] + b2[col];
        float ss = val * val;
#pragma unroll
        for (int off = 1; off < 16; off <<= 1) ss += __shfl_xor(ss, off);
        const float ev = val / fmaxf(sqrtf(ss), 1e-12f);
        const size_t gidx = (size_t)(row0 + row) * 16 + col;
        emb_h[gidx] = (ushort_t)f2bf(ev);
        emb_f[gidx] = ev;
    }
}

// ---------------- cluster means: segmented fp32 sum of emb rows + l2norm ----------------
__global__ __launch_bounds__(128) void k_cmeans(const int* __restrict__ nid_sorted, const int* __restrict__ offs_c,
                                                const int* __restrict__ hist_c, const float* __restrict__ emb_f,
                                                float* __restrict__ means) {
    const int c = blockIdx.x, t = threadIdx.x;
    const int base = offs_c[c], n = hist_c[c];
    const int slot = t >> 4, lane = t & 15;
    float s = 0.f;
    for (int i = slot; i < n; i += 8) {
        const int nid = nid_sorted[base + i];
        s += emb_f[(size_t)nid * 16 + lane];
    }
    __shared__ float red[8][16];
    red[slot][lane] = s;
    __syncthreads();
    if (t < 16) {
        float v = 0.f;
#pragma unroll
        for (int k = 0; k < 8; ++k) v += red[k][t];
        v /= fmaxf((float)n, 1.f);
        float sq = v * v;
#pragma unroll
        for (int off = 1; off < 16; off <<= 1) sq += __shfl_xor(sq, off, 16);
        means[c * 16 + t] = v / fmaxf(sqrtf(sq), 1e-12f);
    }
}

// ---------------- bip sort: counting sort of packed (sl<<21)|e by s>>7 ----------------
__global__ __launch_bounds__(512) void k_bip_sort(const int* __restrict__ src, int* __restrict__ cursor_s,
                                                  unsigned* __restrict__ eid_s) {
    __shared__ int h[NBKT];
    __shared__ int base[NBKT];
    const int t = threadIdx.x;
    const int e0 = blockIdx.x * SCH;
    for (int i = t; i < NBKT; i += 512) h[i] = 0;
    __syncthreads();
    for (int i = t; i < SCH; i += 512) atomicAdd(&h[src[e0 + i] >> 7], 1);
    __syncthreads();
    for (int i = t; i < NBKT; i += 512) {
        const int c = h[i];
        if (c) base[i] = atomicAdd(&cursor_s[i], c);
        h[i] = 0;
    }
    __syncthreads();
    for (int i = t; i < SCH; i += 512) {
        const int e = e0 + i;
        const int s = src[e];
        const int b = s >> 7;
        const int rank = atomicAdd(&h[b], 1);
        eid_s[base[b] + rank] = ((unsigned)(s & 127) << 21) | (unsigned)e;
    }
}

// ---------------- bip segmented: per-bucket dot + max/min + exp + sum + w (LDS only) ----------------
__global__ __launch_bounds__(512) void k_bip_seg(const unsigned* __restrict__ eid_s, const int* __restrict__ offs_s,
                                                 const int* __restrict__ hist_s,
                                                 const int* __restrict__ bdst, const ushort_t* __restrict__ emb_h,
                                                 const float* __restrict__ means, float* __restrict__ att) {
    const int b = blockIdx.x, t = threadIdx.x;
    const int base = offs_s[b], n = hist_s[b];
    const int s0 = b << 7;
    __shared__ unsigned mxs[128], mns[128];
    __shared__ float sms[128];
    if (t < 128) { mxs[t] = 0u; mns[t] = 0xFFFFFFFFu; sms[t] = 0.f; }
    __syncthreads();
    float dv[8];
    int sl[8], ev[8];
#pragma unroll
    for (int k = 0; k < 8; ++k) {
        const int i = k * 512 + t;
        if (i < n) {
            const unsigned pk = eid_s[base + i];
            const int e = (int)(pk & 0x1FFFFFu);
            const int slv = (int)(pk >> 21);
            const int d = bdst[e];
            const float dot = dot16(emb_h, means, s0 + slv, d);
            dv[k] = dot; sl[k] = slv; ev[k] = e;
            const unsigned enc = fenc(dot);
            atomicMax(&mxs[slv], enc);
            atomicMin(&mns[slv], enc);
        }
    }
    for (int i = 4096 + t; i < n; i += 512) {
        const unsigned pk = eid_s[base + i];
        const int e = (int)(pk & 0x1FFFFFu);
        const int slv = (int)(pk >> 21);
        const float dot = dot16(emb_h, means, s0 + slv, bdst[e]);
        const unsigned enc = fenc(dot);
        atomicMax(&mxs[slv], enc);
        atomicMin(&mns[slv], enc);
    }
    __syncthreads();
#pragma unroll
    for (int k = 0; k < 8; ++k) {
        const int i = k * 512 + t;
        if (i < n) {
            const float mx = fdec(mxs[sl[k]]), mn = fdec(mns[sl[k]]);
            const float a = __expf(2.f * (dv[k] - mn) / (EPSA + (mx - mn)));
            dv[k] = a;
            atomicAdd(&sms[sl[k]], a);
        }
    }
    for (int i = 4096 + t; i < n; i += 512) {
        const unsigned pk = eid_s[base + i];
        const int e = (int)(pk & 0x1FFFFFu);
        const int slv = (int)(pk >> 21);
        const float dot = dot16(emb_h, means, s0 + slv, bdst[e]);
        const float mx = fdec(mxs[slv]), mn = fdec(mns[slv]);
        atomicAdd(&sms[slv], __expf(2.f * (dot - mn) / (EPSA + (mx - mn))));
    }
    __syncthreads();
#pragma unroll
    for (int k = 0; k < 8; ++k) {
        const int i = k * 512 + t;
        if (i < n) att[ev[k]] = dv[k] / (EPSA + sms[sl[k]]);
    }
    for (int i = 4096 + t; i < n; i += 512) {
        const unsigned pk = eid_s[base + i];
        const int e = (int)(pk & 0x1FFFFFu);
        const int slv = (int)(pk >> 21);
        const float dot = dot16(emb_h, means, s0 + slv, bdst[e]);
        const float mx = fdec(mxs[slv]), mn = fdec(mns[slv]);
        const float a = __expf(2.f * (dot - mn) / (EPSA + (mx - mn)));
        att[e] = a / (EPSA + sms[slv]);
    }
}

// ---------------- pass C: dst counting-sort scatter (att already = w) ----------------
__global__ __launch_bounds__(512) void k_bip_scatter(const int* __restrict__ src, const int* __restrict__ dst,
                                                     const float* __restrict__ att,
                                                     int* __restrict__ cursor, int* __restrict__ src_sorted,
                                                     ushort_t* __restrict__ w_sorted) {
    __shared__ int h[CC];
    __shared__ int base[CC];
    const int t = threadIdx.x;
    const int e0 = blockIdx.x * SCH;
    for (int i = t; i < CC; i += 512) h[i] = 0;
    __syncthreads();
    for (int i = t; i < SCH; i += 512) atomicAdd(&h[dst[e0 + i]], 1);
    __syncthreads();
    for (int i = t; i < CC; i += 512) {
        const int c = h[i];
        if (c) base[i] = atomicAdd(&cursor[i], c);
        h[i] = 0;
    }
    __syncthreads();
    for (int i = t; i < SCH; i += 512) {
        const int e = e0 + i;
        const int s = src[e], d = dst[e];
        const float w = att[e];
        const int rank = atomicAdd(&h[d], 1);
        const int pos = base[d] + rank;
        src_sorted[pos] = s;
        w_sorted[pos] = (ushort_t)f2bf(w);
    }
}

// ---------------- supernode accumulation, bf16 rows + bf16 w, 4-deep ILP ----------------
__global__ __launch_bounds__(256) void k_supernode_h(const int* __restrict__ src_sorted,
                                                     const ushort_t* __restrict__ w_sorted,
                                                     const int* __restrict__ offs, const int* __restrict__ hist,
                                                     const ushort_t* __restrict__ nodes_h,
                                                     float* __restrict__ out_sn) {
    const int c = blockIdx.x, t = threadIdx.x;
    const int base = offs[c], n = hist[c];
    const int slot = t >> 5, lane = t & 31;
    const ushort4* nh4 = (const ushort4*)nodes_h;
    float4 aA = make_float4(0.f, 0.f, 0.f, 0.f);
    float4 aB = make_float4(0.f, 0.f, 0.f, 0.f);
    float4 aC = make_float4(0.f, 0.f, 0.f, 0.f);
    float4 aD = make_float4(0.f, 0.f, 0.f, 0.f);
    int i0 = 0;
    for (; i0 + 32 <= n; i0 += 32) {
        {
            const int idx = base + i0 + slot;
            const float w = bf2f(w_sorted[idx]);
            const ushort4 v = nh4[(size_t)src_sorted[idx] * 32 + lane];
            aA.x = fmaf(w, bf2f(v.x), aA.x); aA.y = fmaf(w, bf2f(v.y), aA.y);
            aA.z = fmaf(w, bf2f(v.z), aA.z); aA.w = fmaf(w, bf2f(v.w), aA.w);
        }
        {
            const int idx = base + i0 + 8 + slot;
            const float w = bf2f(w_sorted[idx]);
            const ushort4 v = nh4[(size_t)src_sorted[idx] * 32 + lane];
            aB.x = fmaf(w, bf2f(v.x), aB.x); aB.y = fmaf(w, bf2f(v.y), aB.y);
            aB.z = fmaf(w, bf2f(v.z), aB.z); aB.w = fmaf(w, bf2f(v.w), aB.w);
        }
        {
            const int idx = base + i0 + 16 + slot;
            const float w = bf2f(w_sorted[idx]);
            const ushort4 v = nh4[(size_t)src_sorted[idx] * 32 + lane];
            aC.x = fmaf(w, bf2f(v.x), aC.x); aC.y = fmaf(w, bf2f(v.y), aC.y);
            aC.z = fmaf(w, bf2f(v.z), aC.z); aC.w = fmaf(w, bf2f(v.w), aC.w);
        }
        {
            const int idx = base + i0 + 24 + slot;
            const float w = bf2f(w_sorted[idx]);
            const ushort4 v = nh4[(size_t)src_sorted[idx] * 32 + lane];
            aD.x = fmaf(w, bf2f(v.x), aD.x); aD.y = fmaf(w, bf2f(v.y), aD.y);
            aD.z = fmaf(w, bf2f(v.z), aD.z); aD.w = fmaf(w, bf2f(v.w), aD.w);
        }
    }
    for (; i0 < n; i0 += 8) {
        if (i0 + slot < n) {
            const int idx = base + i0 + slot;
            const float w = bf2f(w_sorted[idx]);
            const ushort4 v = nh4[(size_t)src_sorted[idx] * 32 + lane];
            aA.x = fmaf(w, bf2f(v.x), aA.x); aA.y = fmaf(w, bf2f(v.y), aA.y);
            aA.z = fmaf(w, bf2f(v.z), aA.z); aA.w = fmaf(w, bf2f(v.w), aA.w);
        }
    }
    __shared__ float4 red[256];
    red[t] = make_float4((aA.x + aB.x) + (aC.x + aD.x), (aA.y + aB.y) + (aC.y + aD.y),
                         (aA.z + aB.z) + (aC.z + aD.z), (aA.w + aB.w) + (aC.w + aD.w));
    __syncthreads();
    if (t < 32) {
        float4 r = red[t];
#pragma unroll
        for (int k2 = 1; k2 < 8; ++k2) {
            const float4 o = red[t + 32 * k2];
            r.x += o.x; r.y += o.y; r.z += o.z; r.w += o.w;
        }
        ((float4*)(out_sn + (size_t)c * 128))[t] = r;
    }
}

// ---------------- supernode fp32-nodes fallback (ws too small) ----------------
__global__ __launch_bounds__(256) void k_supernode(const int* __restrict__ src_sorted,
                                                   const ushort_t* __restrict__ w_sorted,
                                                   const int* __restrict__ offs, const int* __restrict__ hist,
                                                   const float* __restrict__ nodes, float* __restrict__ out_sn) {
    const int c = blockIdx.x, t = threadIdx.x;
    const int base = offs[c], n = hist[c];
    const int slot = t >> 5, lane = t & 31;
    const float4* nodes4 = (const float4*)nodes;
    float4 aA = make_float4(0.f, 0.f, 0.f, 0.f);
    int i0 = 0;
    for (; i0 < n; i0 += 8) {
        if (i0 + slot < n) {
            const int idx = base + i0 + slot;
            const float w = bf2f(w_sorted[idx]);
            const float4 v = nodes4[(size_t)src_sorted[idx] * 32 + lane];
            aA.x = fmaf(w, v.x, aA.x); aA.y = fmaf(w, v.y, aA.y);
            aA.z = fmaf(w, v.z, aA.z); aA.w = fmaf(w, v.w, aA.w);
        }
    }
    __shared__ float4 red[256];
    red[t] = aA;
    __syncthreads();
    if (t < 32) {
        float4 r = red[t];
#pragma unroll
        for (int k2 = 1; k2 < 8; ++k2) {
            const float4 o = red[t + 32 * k2];
            r.x += o.x; r.y += o.y; r.z += o.z; r.w += o.w;
        }
        ((float4*)(out_sn + (size_t)c * 128))[t] = r;
    }
}

// ---------------- supergraph attention ----------------
__global__ __launch_bounds__(256) void k_sup_dot(const int* __restrict__ ss, const int* __restrict__ sd,
                                                 const float* __restrict__ means, float* __restrict__ satt,
                                                 unsigned* __restrict__ smax, unsigned* __restrict__ smin) {
    const int e = blockIdx.x * 256 + threadIdx.x;
    if (e >= ESN) return;
    const int s = ss[e], d = sd[e];
    const float4* av = (const float4*)(means + (size_t)s * 16);
    const float4* bv = (const float4*)(means + (size_t)d * 16);
    float dot = 0.f;
#pragma unroll
    for (int q = 0; q < 4; ++q) {
        const float4 a = av[q], b = bv[q];
        dot += a.x * b.x + a.y * b.y + a.z * b.z + a.w * b.w;
    }
    satt[e] = dot;
    const unsigned enc = fenc(dot);
    atomicMax(&smax[d], enc);
    atomicMin(&smin[d], enc);
}

__global__ __launch_bounds__(256) void k_sup_tanh(const int* __restrict__ sd, float* __restrict__ satt,
                                                  const unsigned* __restrict__ smax,
                                                  const unsigned* __restrict__ smin) {
    const int e = blockIdx.x * 256 + threadIdx.x;
    if (e >= ESN) return;
    const int d = sd[e];
    const float mx = fdec(smax[d]), mn = fdec(smin[d]);
    satt[e] = tanhf(2.f * (satt[e] - mn) / (EPSA + (mx - mn)));
}

// ---------------- superedge encoder (bf16 MFMA): [32 edges/block] ----------------
__global__ __launch_bounds__(256) void k_edge_mlp(
    const int* __restrict__ esv, const int* __restrict__ edv, const float* __restrict__ sn,
    const ushort_t* __restrict__ W1t, const float* __restrict__ b1, const float* __restrict__ g1,
    const float* __restrict__ be1, const ushort_t* __restrict__ W2t, const float* __restrict__ b2,
    const float* __restrict__ g2, const float* __restrict__ be2, float* __restrict__ out_se) {
    __shared__ ushort_t Xe[32 * 256];   // 16 KB, swizzled
    __shared__ ushort_t Hb[32 * 512];   // 32 KB, swizzled
    __shared__ float redS[4][32], redQ[4][32];
    const int tid = threadIdx.x;
    const int e0 = blockIdx.x * 32;

#pragma unroll
    for (int i = 0; i < 4; ++i) {
        const int c = tid + 256 * i;
        const int row = c >> 5, c8 = c & 31;
        const int node = (c8 < 16) ? esv[e0 + row] : edv[e0 + row];
        const float4* gp = (const float4*)(sn + (size_t)node * 128 + (c8 & 15) * 8);
        const float4 u = gp[0], v = gp[1];
        uint4 pk;
        pk.x = f2bf(u.x) | (f2bf(u.y) << 16);
        pk.y = f2bf(u.z) | (f2bf(u.w) << 16);
        pk.z = f2bf(v.x) | (f2bf(v.y) << 16);
        pk.w = f2bf(v.z) | (f2bf(v.w) << 16);
        const int byte = row * 512 + ((c8 * 16) ^ ((row & 7) << 4));
        *(uint4*)((char*)Xe + byte) = pk;
    }
    __syncthreads();

    const int wv = tid >> 6, l = tid & 63;
    const int q = l >> 4, c16 = l & 15;
    const int wcol0 = wv * 128;

    f32x4 acc[2][8];
#pragma unroll
    for (int mt = 0; mt < 2; ++mt)
#pragma unroll
        for (int nt = 0; nt < 8; ++nt) acc[mt][nt] = (f32x4){0.f, 0.f, 0.f, 0.f};

#pragma unroll
    for (int ks = 0; ks < 8; ++ks) {
        bf16x8 af[2];
#pragma unroll
        for (int mt = 0; mt < 2; ++mt) {
            const int row = 16 * mt + c16;
            const int byte = row * 512 + ((64 * ks + 16 * q) ^ ((row & 7) << 4));
            af[mt] = __builtin_bit_cast(bf16x8, *(const uint4*)((const char*)Xe + byte));
        }
#pragma unroll
        for (int nt = 0; nt < 8; ++nt) {
            const int n = wcol0 + 16 * nt + c16;
            const bf16x8 bfr = __builtin_bit_cast(bf16x8, *(const uint4*)(W1t + n * 256 + 32 * ks + 8 * q));
#pragma unroll
            for (int mt = 0; mt < 2; ++mt)
                acc[mt][nt] = __builtin_amdgcn_mfma_f32_16x16x32_bf16(af[mt], bfr, acc[mt][nt], 0, 0, 0);
        }
    }

    float b1v[8], g1v[8], bev[8];
#pragma unroll
    for (int nt = 0; nt < 8; ++nt) {
        const int col = wcol0 + 16 * nt + c16;
        b1v[nt] = b1[col]; g1v[nt] = g1[col]; bev[nt] = be1[col];
    }
    float sS[2][4], sQ[2][4];
#pragma unroll
    for (int mt = 0; mt < 2; ++mt)
#pragma unroll
        for (int r = 0; r < 4; ++r) {
            float s = 0.f, qq = 0.f;
#pragma unroll
            for (int nt = 0; nt < 8; ++nt) {
                const float h = acc[mt][nt][r] + b1v[nt];
                acc[mt][nt][r] = h;
                s += h; qq += h * h;
            }
#pragma unroll
            for (int off = 1; off < 16; off <<= 1) {
                s += __shfl_xor(s, off);
                qq += __shfl_xor(qq, off);
            }
            sS[mt][r] = s; sQ[mt][r] = qq;
        }
    if (c16 == 0) {
#pragma unroll
        for (int mt = 0; mt < 2; ++mt)
#pragma unroll
            for (int r = 0; r < 4; ++r) {
                const int row = 16 * mt + 4 * q + r;
                redS[wv][row] = sS[mt][r];
                redQ[wv][row] = sQ[mt][r];
            }
    }
    __syncthreads();
#pragma unroll
    for (int mt = 0; mt < 2; ++mt)
#pragma unroll
        for (int r = 0; r < 4; ++r) {
            const int row = 16 * mt + 4 * q + r;
            const float S = redS[0][row] + redS[1][row] + redS[2][row] + redS[3][row];
            const float Q = redQ[0][row] + redQ[1][row] + redQ[2][row] + redQ[3][row];
            const float m_ = S * (1.f / 512.f);
            const float iv = rsqrtf(Q * (1.f / 512.f) - m_ * m_ + 1e-5f);
#pragma unroll
            for (int nt = 0; nt < 8; ++nt) {
                const int col = wcol0 + 16 * nt + c16;
                const float rv = fmaxf((acc[mt][nt][r] - m_) * iv * g1v[nt] + bev[nt], 0.f);
                const int byte = row * 1024 + ((col * 2) ^ ((row & 7) << 4));
                *(ushort_t*)((char*)Hb + byte) = (ushort_t)f2bf(rv);
            }
        }
    __syncthreads();

    f32x4 acc2[2][2];
#pragma unroll
    for (int mt = 0; mt < 2; ++mt)
#pragma unroll
        for (int nt = 0; nt < 2; ++nt) acc2[mt][nt] = (f32x4){0.f, 0.f, 0.f, 0.f};
#pragma unroll 4
    for (int ks = 0; ks < 16; ++ks) {
        bf16x8 bfb[2];
#pragma unroll
        for (int nt = 0; nt < 2; ++nt) {
            const int n = wv * 32 + 16 * nt + c16;
            bfb[nt] = __builtin_bit_cast(bf16x8, *(const uint4*)(W2t + n * 512 + 32 * ks + 8 * q));
        }
#pragma unroll
        for (int mt = 0; mt < 2; ++mt) {
            const int row = 16 * mt + c16;
            const int byte = row * 1024 + ((64 * ks + 16 * q) ^ ((row & 7) << 4));
            const bf16x8 ha = __builtin_bit_cast(bf16x8, *(const uint4*)((const char*)Hb + byte));
#pragma unroll
            for (int nt = 0; nt < 2; ++nt)
                acc2[mt][nt] = __builtin_amdgcn_mfma_f32_16x16x32_bf16(ha, bfb[nt], acc2[mt][nt], 0, 0, 0);
        }
    }

    float b2v[2], g2v[2], be2v[2];
#pragma unroll
    for (int nt = 0; nt < 2; ++nt) {
        const int col = wv * 32 + 16 * nt + c16;
        b2v[nt] = b2[col]; g2v[nt] = g2[col]; be2v[nt] = be2[col];
    }
    float sS2[2][4], sQ2[2][4];
#pragma unroll
    for (int mt = 0; mt < 2; ++mt)
#pragma unroll
        for (int r = 0; r < 4; ++r) {
            float s = 0.f, qq = 0.f;
#pragma unroll
            for (int nt = 0; nt < 2; ++nt) {
                const float h = acc2[mt][nt][r] + b2v[nt];
                acc2[mt][nt][r] = h;
                s += h; qq += h * h;
            }
#pragma unroll
            for (int off = 1; off < 16; off <<= 1) {
                s += __shfl_xor(s, off);
                qq += __shfl_xor(qq, off);
            }
            sS2[mt][r] = s; sQ2[mt][r] = qq;
        }
    __syncthreads();
    if (c16 == 0) {
#pragma unroll
        for (int mt = 0; mt < 2; ++mt)
#pragma unroll
            for (int r = 0; r < 4; ++r) {
                const int row = 16 * mt + 4 * q + r;
                redS[wv][row] = sS2[mt][r];
                redQ[wv][row] = sQ2[mt][r];
            }
    }
    __syncthreads();
#pragma unroll
    for (int mt = 0; mt < 2; ++mt)
#pragma unroll
        for (int r = 0; r < 4; ++r) {
            const int row = 16 * mt + 4 * q + r;
            const float S = redS[0][row] + redS[1][row] + redS[2][row] + redS[3][row];
            const float Q = redQ[0][row] + redQ[1][row] + redQ[2][row] + redQ[3][row];
            const float m_ = S * (1.f / 128.f);
            const float iv = rsqrtf(Q * (1.f / 128.f) - m_ * m_ + 1e-5f);
#pragma unroll
            for (int nt = 0; nt < 2; ++nt) {
                const int col = wv * 32 + 16 * nt + c16;
                const float o = fmaxf((acc2[mt][nt][r] - m_) * iv * g2v[nt] + be2v[nt], 0.f);
                out_se[(size_t)(e0 + row) * 128 + col] = o;
            }
        }
}

extern "C" void kernel_launch(void* const* d_in, const int* in_sizes, int n_in,
                              void* d_out, int out_size, void* d_ws, size_t ws_size,
                              hipStream_t stream) {
    const float* nodes = (const float*)d_in[0];
    const int* clusters = (const int*)d_in[1];
    const int* bsrc = (const int*)d_in[2];
    const int* bdst = (const int*)d_in[3];
    const int* susrc = (const int*)d_in[4];
    const int* sudst = (const int*)d_in[5];
    const float* cW1 = (const float*)d_in[6];
    const float* cb1 = (const float*)d_in[7];
    const float* cg1 = (const float*)d_in[8];
    const float* cbe1 = (const float*)d_in[9];
    const float* cW2 = (const float*)d_in[10];
    const float* cb2 = (const float*)d_in[11];
    const float* eW1 = (const float*)d_in[12];
    const float* eb1 = (const float*)d_in[13];
    const float* eg1 = (const float*)d_in[14];
    const float* ebe1 = (const float*)d_in[15];
    const float* eW2 = (const float*)d_in[16];
    const float* eb2 = (const float*)d_in[17];
    const float* eg2 = (const float*)d_in[18];
    const float* ebe2 = (const float*)d_in[19];

    float* out_sn = (float*)d_out;
    float* out_se = out_sn + (size_t)CC * 128;
    float* out_bip = out_se + (size_t)ESN * 128;
    float* out_satt = out_bip + EBN;

    // workspace layout (u32 units)
    int* hist_d = (int*)d_ws;                              // 2000
    int* hist_s = hist_d + 2000;                           // 2000 (NBKT used)
    int* hist_c = hist_s + 2000;                           // 2000
    unsigned* smax = (unsigned*)(hist_c + 2000);           // 2000
    unsigned* smin = smax + 2000;                          // 2000
    ushort_t* emb_h = (ushort_t*)(smin + 2000);            // 3200000 ushort (1.6M u32)
    float* emb_f = (float*)(emb_h + 3200000);              // 3200000 f32
    float* means = emb_f + 3200000;                        // 32000
    int* offs_d = (int*)(means + 32000);                   // 2000
    int* cursor_d = offs_d + 2000;                         // 2000
    int* offs_s = cursor_d + 2000;                         // 2000
    int* cursor_s = offs_s + 2000;                         // 2000
    int* offs_c = cursor_s + 2000;                         // 2000
    int* cursor_c = offs_c + 2000;                         // 2000
    int* nid_sorted = cursor_c + 2000;                     // 200000
    int* src_sorted = nid_sorted + 200000;                 // 2000000 (overlaid: eid_s before pass C)
    ushort_t* w_sorted = (ushort_t*)(src_sorted + 2000000);// 2000000 ushort (1M u32)
    ushort_t* cW1h = w_sorted + 2000000;                   // 65536 fp16
    ushort_t* cW1pad = cW1h + 512 * 128;                   // 65536 (pad)
    ushort_t* cW2h = cW1pad + 512 * 128;                   // 8192 fp16
    ushort_t* cW2pad = cW2h + 16 * 512;                    // 8192 (pad)
    ushort_t* eW1t = cW2pad + 16 * 512;                    // 131072
    ushort_t* eW2t = eW1t + 512 * 256;                     // 65536
    ushort_t* nodes_h = eW2t + 512 * 128;                  // 25600000 bf16 (51.2 MB, optional)
    unsigned* eid_s = (unsigned*)src_sorted;               // alias: dead before src_sorted written

    const size_t need_bytes = ((size_t)(char*)(nodes_h + (size_t)NN * 128) - (size_t)(char*)d_ws);
    const bool use_nh = ws_size >= need_bytes;

    // init: [hist_d|hist_s|hist_c|smax] = 0 ; smin = 0xFF
    hipMemsetAsync(hist_d, 0, (size_t)(2000 + 2000 + 2000 + 2000) * 4, stream);
    hipMemsetAsync(smin, 0xFF, (size_t)2000 * 4, stream);

    k_setup<<<CVB + HSB, 256, 0, stream>>>(cW1, cW2, eW1, eW2, cW1h, cW2h, eW1t, eW2t,
                                           bsrc, bdst, clusters, hist_d, hist_s, hist_c);
    k_scan3<<<3, 1024, 0, stream>>>(hist_d, offs_d, cursor_d, hist_s, offs_s, cursor_s,
                                    hist_c, offs_c, cursor_c);
    k_nsort<<<NN / 8000, 512, 0, stream>>>(clusters, cursor_c, nid_sorted);
    k_mlp1<<<NN / 32, 256, 0, stream>>>(nodes, cW1h, cb1, cg1, cbe1, cW2h, cb2,
                                        emb_h, emb_f, use_nh ? nodes_h : (ushort_t*)nullptr);
    k_cmeans<<<CC, 128, 0, stream>>>(nid_sorted, offs_c, hist_c, emb_f, means);
    k_bip_sort<<<EBN / SCH, 512, 0, stream>>>(bsrc, cursor_s, eid_s);
    k_bip_seg<<<NBKT, 512, 0, stream>>>(eid_s, offs_s, hist_s, bdst, emb_h, means, out_bip);
    k_bip_scatter<<<EBN / SCH, 512, 0, stream>>>(bsrc, bdst, out_bip, cursor_d, src_sorted, w_sorted);
    if (use_nh)
        k_supernode_h<<<CC, 256, 0, stream>>>(src_sorted, w_sorted, offs_d, hist_d, nodes_h, out_sn);
    else
        k_supernode<<<CC, 256, 0, stream>>>(src_sorted, w_sorted, offs_d, hist_d, nodes, out_sn);
    k_sup_dot<<<(ESN + 255) / 256, 256, 0, stream>>>(susrc, sudst, means, out_satt, smax, smin);
    k_sup_tanh<<<(ESN + 255) / 256, 256, 0, stream>>>(sudst, out_satt, smax, smin);
    k_edge_mlp<<<ESN / 32, 256, 0, stream>>>(susrc, sudst, out_sn, eW1t, eb1, eg1, ebe1, eW2t, eb2, eg2, ebe2, out_se);
}

// Round 21
// 501.615 us; speedup vs baseline: 1.0400x; 1.0400x over previous
//
#include <hip/hip_runtime.h>

#define NN 200000
#define CC 2000
#define EBN 2000000
#define ESN 40000
#define EPSA 1e-4f
#define SCH 8000
#define NBKT 1563
#define CVB 1056
#define HSB 977

typedef unsigned short ushort_t;
typedef float f32x4 __attribute__((ext_vector_type(4)));
typedef __bf16 bf16x8 __attribute__((ext_vector_type(8)));
typedef _Float16 f16x8 __attribute__((ext_vector_type(8)));

__device__ __forceinline__ unsigned fenc(float f) {
    unsigned b = __float_as_uint(f);
    return (b & 0x80000000u) ? ~b : (b | 0x80000000u);
}
__device__ __forceinline__ float fdec(unsigned u) {
    return (u & 0x80000000u) ? __uint_as_float(u ^ 0x80000000u) : __uint_as_float(~u);
}
__device__ __forceinline__ unsigned f2bf(float f) {  // RNE f32 -> bf16 bits
    unsigned u = __float_as_uint(f);
    return (u + 0x7fffu + ((u >> 16) & 1u)) >> 16;
}
__device__ __forceinline__ float bf2f(ushort_t u) { return __uint_as_float(((unsigned)u) << 16); }
__device__ __forceinline__ ushort_t f2h(float f) {
    const _Float16 h = (_Float16)f;
    return __builtin_bit_cast(ushort_t, h);
}
__device__ __forceinline__ float dot16(const ushort_t* __restrict__ emb_h, const float* __restrict__ means,
                                       int s, int d) {
    const uint4 e0v = *(const uint4*)(emb_h + (size_t)s * 16);
    const uint4 e1v = *(const uint4*)(emb_h + (size_t)s * 16 + 8);
    const float4* mv = (const float4*)(means + (size_t)d * 16);
    const float4 m0 = mv[0], m1 = mv[1], m2 = mv[2], m3 = mv[3];
    float dot = 0.f;
    dot += bf2f((ushort_t)(e0v.x & 0xFFFF)) * m0.x + bf2f((ushort_t)(e0v.x >> 16)) * m0.y;
    dot += bf2f((ushort_t)(e0v.y & 0xFFFF)) * m0.z + bf2f((ushort_t)(e0v.y >> 16)) * m0.w;
    dot += bf2f((ushort_t)(e0v.z & 0xFFFF)) * m1.x + bf2f((ushort_t)(e0v.z >> 16)) * m1.y;
    dot += bf2f((ushort_t)(e0v.w & 0xFFFF)) * m1.z + bf2f((ushort_t)(e0v.w >> 16)) * m1.w;
    dot += bf2f((ushort_t)(e1v.x & 0xFFFF)) * m2.x + bf2f((ushort_t)(e1v.x >> 16)) * m2.y;
    dot += bf2f((ushort_t)(e1v.y & 0xFFFF)) * m2.z + bf2f((ushort_t)(e1v.y >> 16)) * m2.w;
    dot += bf2f((ushort_t)(e1v.z & 0xFFFF)) * m3.x + bf2f((ushort_t)(e1v.z >> 16)) * m3.y;
    dot += bf2f((ushort_t)(e1v.w & 0xFFFF)) * m3.z + bf2f((ushort_t)(e1v.w >> 16)) * m3.w;
    return dot;
}

// ---- fused setup: weight convert (blocks 0..CVB-1) + dual histogram (blocks CVB..) ----
__global__ __launch_bounds__(256) void k_setup(const float* __restrict__ cW1, const float* __restrict__ cW2,
                                               const float* __restrict__ eW1, const float* __restrict__ eW2,
                                               ushort_t* __restrict__ cW1h, ushort_t* __restrict__ cW2h,
                                               ushort_t* __restrict__ eW1t, ushort_t* __restrict__ eW2t,
                                               const int* __restrict__ bsrc, const int* __restrict__ bdst,
                                               int* __restrict__ hist_d, int* __restrict__ hist_s) {
    __shared__ int hd[CC];
    __shared__ int hs[NBKT];
    if (blockIdx.x < CVB) {
        int id = blockIdx.x * 256 + threadIdx.x;
        if (id < 65536) {
            const int n = id >> 7, k = id & 127;
            cW1h[id] = f2h(cW1[k * 512 + n]);
            return;
        }
        id -= 65536;
        if (id < 8192) {
            const int n = id >> 9, k = id & 511;
            cW2h[id] = f2h(cW2[k * 16 + n]);
            return;
        }
        id -= 8192;
        if (id < 131072) { const int n = id >> 8, k = id & 255; eW1t[id] = (ushort_t)f2bf(eW1[k * 512 + n]); return; }
        id -= 131072;
        if (id < 65536) { const int n = id >> 9, k = id & 511; eW2t[id] = (ushort_t)f2bf(eW2[k * 128 + n]); return; }
        return;
    }
    const int t = threadIdx.x;
    for (int i = t; i < CC; i += 256) hd[i] = 0;
    for (int i = t; i < NBKT; i += 256) hs[i] = 0;
    __syncthreads();
    for (int e = (blockIdx.x - CVB) * 256 + t; e < EBN; e += HSB * 256) {
        atomicAdd(&hd[bdst[e]], 1);
        atomicAdd(&hs[bsrc[e] >> 7], 1);
    }
    __syncthreads();
    for (int i = t; i < CC; i += 256) if (hd[i]) atomicAdd(&hist_d[i], hd[i]);
    for (int i = t; i < NBKT; i += 256) if (hs[i]) atomicAdd(&hist_s[i], hs[i]);
}

// ---------------- dual exclusive scan ----------------
__global__ __launch_bounds__(1024) void k_scan2(const int* __restrict__ hist_d, int* __restrict__ offs_d,
                                                int* __restrict__ cursor_d, const int* __restrict__ hist_s,
                                                int* __restrict__ offs_s, int* __restrict__ cursor_s) {
    const int* hist = blockIdx.x ? hist_s : hist_d;
    int* offs = blockIdx.x ? offs_s : offs_d;
    int* cursor = blockIdx.x ? cursor_s : cursor_d;
    const int n = blockIdx.x ? NBKT : CC;
    __shared__ int buf[2][2048];
    const int t = threadIdx.x;
    buf[0][t]        = (t        < n) ? hist[t]        : 0;
    buf[0][t + 1024] = (t + 1024 < n) ? hist[t + 1024] : 0;
    __syncthreads();
    int pp = 0;
    for (int off = 1; off < 2048; off <<= 1) {
        const int np = pp ^ 1;
        for (int i = t; i < 2048; i += 1024) {
            int v = buf[pp][i];
            if (i >= off) v += buf[pp][i - off];
            buf[np][i] = v;
        }
        pp = np;
        __syncthreads();
    }
    for (int i = t; i < n; i += 1024) {
        const int ex = (i == 0) ? 0 : buf[pp][i - 1];
        offs[i] = ex;
        cursor[i] = ex;
    }
}

// ---------------- node MLP: single-fp16 MFMA both phases + bf16 node/emb emits ----------------
__global__ __launch_bounds__(256, 3) void k_mlp1(
    const float* __restrict__ nodes, const int* __restrict__ clusters,
    const ushort_t* __restrict__ W1h, const float* __restrict__ b1,
    const float* __restrict__ g1, const float* __restrict__ be1,
    const ushort_t* __restrict__ W2h, const float* __restrict__ b2,
    ushort_t* __restrict__ emb_h, float* __restrict__ sums, float* __restrict__ cnt,
    ushort_t* __restrict__ nodes_h) {
    __shared__ char Ubuf[16384];
    __shared__ float redS[4][32], redQ[4][32];
    ushort_t* Xh = (ushort_t*)Ubuf;
    const int tid = threadIdx.x;
    const int row0 = blockIdx.x * 32;

#pragma unroll
    for (int i = 0; i < 2; ++i) {
        const int c = tid + 256 * i;
        const int row = c >> 4, c8 = c & 15;
        const float4* gp = (const float4*)(nodes + (size_t)(row0 + row) * 128 + c8 * 8);
        const float4 u = gp[0], v = gp[1];
        uint4 pkh;
        pkh.x = f2h(u.x) | ((unsigned)f2h(u.y) << 16);
        pkh.y = f2h(u.z) | ((unsigned)f2h(u.w) << 16);
        pkh.z = f2h(v.x) | ((unsigned)f2h(v.y) << 16);
        pkh.w = f2h(v.z) | ((unsigned)f2h(v.w) << 16);
        const int byte = row * 256 + ((c8 * 16) ^ ((row & 7) << 4));
        *(uint4*)((char*)Xh + byte) = pkh;
        if (nodes_h) {
            uint4 pkb;
            pkb.x = f2bf(u.x) | (f2bf(u.y) << 16);
            pkb.y = f2bf(u.z) | (f2bf(u.w) << 16);
            pkb.z = f2bf(v.x) | (f2bf(v.y) << 16);
            pkb.w = f2bf(v.z) | (f2bf(v.w) << 16);
            ((uint4*)nodes_h)[(size_t)(row0 + row) * 16 + c8] = pkb;
        }
    }
    __syncthreads();

    const int wv = tid >> 6, l = tid & 63;
    const int q = l >> 4, c16 = l & 15;
    const int wcol0 = wv * 128;

    f32x4 acc[2][8];
#pragma unroll
    for (int mt = 0; mt < 2; ++mt)
#pragma unroll
        for (int nt = 0; nt < 8; ++nt) acc[mt][nt] = (f32x4){0.f, 0.f, 0.f, 0.f};

#pragma unroll
    for (int ks = 0; ks < 4; ++ks) {
        f16x8 ah[2];
#pragma unroll
        for (int mt = 0; mt < 2; ++mt) {
            const int row = 16 * mt + c16;
            const int byte = row * 256 + ((64 * ks + 16 * q) ^ ((row & 7) << 4));
            ah[mt] = __builtin_bit_cast(f16x8, *(const uint4*)((const char*)Xh + byte));
        }
#pragma unroll
        for (int nt = 0; nt < 8; ++nt) {
            const int n = wcol0 + 16 * nt + c16;
            const f16x8 bh = __builtin_bit_cast(f16x8, *(const uint4*)(W1h + n * 128 + 32 * ks + 8 * q));
#pragma unroll
            for (int mt = 0; mt < 2; ++mt)
                acc[mt][nt] = __builtin_amdgcn_mfma_f32_16x16x32_f16(ah[mt], bh, acc[mt][nt], 0, 0, 0);
        }
    }

    float b1v[8], g1v[8], bev[8];
#pragma unroll
    for (int nt = 0; nt < 8; ++nt) {
        const int col = wcol0 + 16 * nt + c16;
        b1v[nt] = b1[col]; g1v[nt] = g1[col]; bev[nt] = be1[col];
    }
    float sS[2][4], sQ[2][4];
#pragma unroll
    for (int mt = 0; mt < 2; ++mt)
#pragma unroll
        for (int r = 0; r < 4; ++r) {
            float s = 0.f, qq = 0.f;
#pragma unroll
            for (int nt = 0; nt < 8; ++nt) {
                const float h = acc[mt][nt][r] + b1v[nt];
                acc[mt][nt][r] = h;
                s += h; qq += h * h;
            }
#pragma unroll
            for (int off = 1; off < 16; off <<= 1) {
                s += __shfl_xor(s, off);
                qq += __shfl_xor(qq, off);
            }
            sS[mt][r] = s; sQ[mt][r] = qq;
        }
    if (c16 == 0) {
#pragma unroll
        for (int mt = 0; mt < 2; ++mt)
#pragma unroll
            for (int r = 0; r < 4; ++r) {
                const int row = 16 * mt + 4 * q + r;
                redS[wv][row] = sS[mt][r];
                redQ[wv][row] = sQ[mt][r];
            }
    }
    __syncthreads();

    float mean[2][4], inv[2][4];
#pragma unroll
    for (int mt = 0; mt < 2; ++mt)
#pragma unroll
        for (int r = 0; r < 4; ++r) {
            const int row = 16 * mt + 4 * q + r;
            const float S = redS[0][row] + redS[1][row] + redS[2][row] + redS[3][row];
            const float Q = redQ[0][row] + redQ[1][row] + redQ[2][row] + redQ[3][row];
            const float m_ = S * (1.f / 512.f);
            mean[mt][r] = m_;
            inv[mt][r] = rsqrtf(Q * (1.f / 512.f) - m_ * m_ + 1e-5f);
        }

    ushort_t* Hw = (ushort_t*)(Ubuf + 8192 + wv * 2048);
    f32x4 acc2[2];
    acc2[0] = (f32x4){0.f, 0.f, 0.f, 0.f};
    acc2[1] = (f32x4){0.f, 0.f, 0.f, 0.f};
#pragma unroll
    for (int ch = 0; ch < 4; ++ch) {
#pragma unroll
        for (int mt = 0; mt < 2; ++mt)
#pragma unroll
            for (int r = 0; r < 4; ++r) {
                const int row = 16 * mt + 4 * q + r;
                const int swz = (((row >> 2) & 1) << 3) | (((row >> 3) & 1) << 4);
#pragma unroll
                for (int ntl = 0; ntl < 2; ++ntl) {
                    const int nt = 2 * ch + ntl;
                    const float rv = fmaxf((acc[mt][nt][r] - mean[mt][r]) * inv[mt][r] * g1v[nt] + bev[nt], 0.f);
                    Hw[row * 32 + ((16 * ntl + c16) ^ swz)] = f2h(rv);
                }
            }
        const int kg = wcol0 + 32 * ch + 8 * q;
        const f16x8 bh = __builtin_bit_cast(f16x8, *(const uint4*)(W2h + c16 * 512 + kg));
#pragma unroll
        for (int mt = 0; mt < 2; ++mt) {
            const int row = 16 * mt + c16;
            const int swz = (((row >> 2) & 1) << 3) | (((row >> 3) & 1) << 4);
            const int ci = (8 * q) ^ swz;
            const f16x8 ah = __builtin_bit_cast(f16x8, *(const uint4*)(Hw + row * 32 + ci));
            acc2[mt] = __builtin_amdgcn_mfma_f32_16x16x32_f16(ah, bh, acc2[mt], 0, 0, 0);
        }
    }
    __syncthreads();

    float* Cb = (float*)Ubuf;  // [4][32][16] = 8 KB
#pragma unroll
    for (int mt = 0; mt < 2; ++mt)
#pragma unroll
        for (int r = 0; r < 4; ++r) Cb[(wv * 32 + 16 * mt + 4 * q + r) * 16 + c16] = acc2[mt][r];
    __syncthreads();

#pragma unroll
    for (int rep = 0; rep < 2; ++rep) {
        const int slot = tid + 256 * rep;
        const int row = slot >> 4, col = slot & 15;
        float val = Cb[(0 * 32 + row) * 16 + col] + Cb[(1 * 32 + row) * 16 + col] +
                    Cb[(2 * 32 + row) * 16 + col] + Cb[(3 * 32 + row) * 16 + col] + b2[col];
        float ss = val * val;
#pragma unroll
        for (int off = 1; off < 16; off <<= 1) ss += __shfl_xor(ss, off);
        const float ev = val / fmaxf(sqrtf(ss), 1e-12f);
        const int grow = row0 + row;
        emb_h[(size_t)grow * 16 + col] = (ushort_t)f2bf(ev);
        const int cl = clusters[grow];
        if (cl >= 0) {
            atomicAdd(&sums[cl * 16 + col], ev);
            if (col == 0) atomicAdd(&cnt[cl], 1.f);
        }
    }
}

// ---------------- cluster means + l2norm ----------------
__global__ __launch_bounds__(256) void k_means(const float* __restrict__ sums, const float* __restrict__ cnt,
                                               float* __restrict__ means) {
    const int t = blockIdx.x * 256 + threadIdx.x;
    const int c = t >> 4;
    const float v = sums[t] / fmaxf(cnt[c], 1.f);
    float sq = v * v;
#pragma unroll
    for (int off = 1; off < 16; off <<= 1) sq += __shfl_xor(sq, off, 16);
    means[t] = v / fmaxf(sqrtf(sq), 1e-12f);
}

// ---------------- bip sort: counting sort of packed (sl<<21)|e by s>>7 ----------------
__global__ __launch_bounds__(512) void k_bip_sort(const int* __restrict__ src, int* __restrict__ cursor_s,
                                                  unsigned* __restrict__ eid_s) {
    __shared__ int h[NBKT];
    __shared__ int base[NBKT];
    const int t = threadIdx.x;
    const int e0 = blockIdx.x * SCH;
    for (int i = t; i < NBKT; i += 512) h[i] = 0;
    __syncthreads();
    for (int i = t; i < SCH; i += 512) atomicAdd(&h[src[e0 + i] >> 7], 1);
    __syncthreads();
    for (int i = t; i < NBKT; i += 512) {
        const int c = h[i];
        if (c) base[i] = atomicAdd(&cursor_s[i], c);
        h[i] = 0;
    }
    __syncthreads();
    for (int i = t; i < SCH; i += 512) {
        const int e = e0 + i;
        const int s = src[e];
        const int b = s >> 7;
        const int rank = atomicAdd(&h[b], 1);
        eid_s[base[b] + rank] = ((unsigned)(s & 127) << 21) | (unsigned)e;
    }
}

// ---------------- bip segmented: per-bucket dot + max/min + exp + sum + w (LDS only) ----------------
__global__ __launch_bounds__(512) void k_bip_seg(const unsigned* __restrict__ eid_s, const int* __restrict__ offs_s,
                                                 const int* __restrict__ hist_s,
                                                 const int* __restrict__ bdst, const ushort_t* __restrict__ emb_h,
                                                 const float* __restrict__ means, float* __restrict__ att) {
    const int b = blockIdx.x, t = threadIdx.x;
    const int base = offs_s[b], n = hist_s[b];
    const int s0 = b << 7;
    __shared__ unsigned mxs[128], mns[128];
    __shared__ float sms[128];
    if (t < 128) { mxs[t] = 0u; mns[t] = 0xFFFFFFFFu; sms[t] = 0.f; }
    __syncthreads();
    float dv[8];
    int sl[8], ev[8];
#pragma unroll
    for (int k = 0; k < 8; ++k) {
        const int i = k * 512 + t;
        if (i < n) {
            const unsigned pk = eid_s[base + i];
            const int e = (int)(pk & 0x1FFFFFu);
            const int slv = (int)(pk >> 21);
            const int d = bdst[e];
            const float dot = dot16(emb_h, means, s0 + slv, d);
            dv[k] = dot; sl[k] = slv; ev[k] = e;
            const unsigned enc = fenc(dot);
            atomicMax(&mxs[slv], enc);
            atomicMin(&mns[slv], enc);
        }
    }
    for (int i = 4096 + t; i < n; i += 512) {
        const unsigned pk = eid_s[base + i];
        const int e = (int)(pk & 0x1FFFFFu);
        const int slv = (int)(pk >> 21);
        const float dot = dot16(emb_h, means, s0 + slv, bdst[e]);
        const unsigned enc = fenc(dot);
        atomicMax(&mxs[slv], enc);
        atomicMin(&mns[slv], enc);
    }
    __syncthreads();
#pragma unroll
    for (int k = 0; k < 8; ++k) {
        const int i = k * 512 + t;
        if (i < n) {
            const float mx = fdec(mxs[sl[k]]), mn = fdec(mns[sl[k]]);
            const float a = __expf(2.f * (dv[k] - mn) / (EPSA + (mx - mn)));
            dv[k] = a;
            atomicAdd(&sms[sl[k]], a);
        }
    }
    for (int i = 4096 + t; i < n; i += 512) {
        const unsigned pk = eid_s[base + i];
        const int e = (int)(pk & 0x1FFFFFu);
        const int slv = (int)(pk >> 21);
        const float dot = dot16(emb_h, means, s0 + slv, bdst[e]);
        const float mx = fdec(mxs[slv]), mn = fdec(mns[slv]);
        atomicAdd(&sms[slv], __expf(2.f * (dot - mn) / (EPSA + (mx - mn))));
    }
    __syncthreads();
#pragma unroll
    for (int k = 0; k < 8; ++k) {
        const int i = k * 512 + t;
        if (i < n) att[ev[k]] = dv[k] / (EPSA + sms[sl[k]]);
    }
    for (int i = 4096 + t; i < n; i += 512) {
        const unsigned pk = eid_s[base + i];
        const int e = (int)(pk & 0x1FFFFFu);
        const int slv = (int)(pk >> 21);
        const float dot = dot16(emb_h, means, s0 + slv, bdst[e]);
        const float mx = fdec(mxs[slv]), mn = fdec(mns[slv]);
        const float a = __expf(2.f * (dot - mn) / (EPSA + (mx - mn)));
        att[e] = a / (EPSA + sms[slv]);
    }
}

// ---------------- pass C: dst counting-sort scatter (att already = w) ----------------
__global__ __launch_bounds__(512) void k_bip_scatter(const int* __restrict__ src, const int* __restrict__ dst,
                                                     const float* __restrict__ att,
                                                     int* __restrict__ cursor, int* __restrict__ src_sorted,
                                                     ushort_t* __restrict__ w_sorted) {
    __shared__ int h[CC];
    __shared__ int base[CC];
    const int t = threadIdx.x;
    const int e0 = blockIdx.x * SCH;
    for (int i = t; i < CC; i += 512) h[i] = 0;
    __syncthreads();
    for (int i = t; i < SCH; i += 512) atomicAdd(&h[dst[e0 + i]], 1);
    __syncthreads();
    for (int i = t; i < CC; i += 512) {
        const int c = h[i];
        if (c) base[i] = atomicAdd(&cursor[i], c);
        h[i] = 0;
    }
    __syncthreads();
    for (int i = t; i < SCH; i += 512) {
        const int e = e0 + i;
        const int s = src[e], d = dst[e];
        const float w = att[e];
        const int rank = atomicAdd(&h[d], 1);
        const int pos = base[d] + rank;
        src_sorted[pos] = s;
        w_sorted[pos] = (ushort_t)f2bf(w);
    }
}

// ---------------- supernode accumulation, bf16 rows + bf16 w, 4-deep ILP ----------------
__global__ __launch_bounds__(256) void k_supernode_h(const int* __restrict__ src_sorted,
                                                     const ushort_t* __restrict__ w_sorted,
                                                     const int* __restrict__ offs, const int* __restrict__ hist,
                                                     const ushort_t* __restrict__ nodes_h,
                                                     float* __restrict__ out_sn) {
    const int c = blockIdx.x, t = threadIdx.x;
    const int base = offs[c], n = hist[c];
    const int slot = t >> 5, lane = t & 31;
    const ushort4* nh4 = (const ushort4*)nodes_h;
    float4 aA = make_float4(0.f, 0.f, 0.f, 0.f);
    float4 aB = make_float4(0.f, 0.f, 0.f, 0.f);
    float4 aC = make_float4(0.f, 0.f, 0.f, 0.f);
    float4 aD = make_float4(0.f, 0.f, 0.f, 0.f);
    int i0 = 0;
    for (; i0 + 32 <= n; i0 += 32) {
        {
            const int idx = base + i0 + slot;
            const float w = bf2f(w_sorted[idx]);
            const ushort4 v = nh4[(size_t)src_sorted[idx] * 32 + lane];
            aA.x = fmaf(w, bf2f(v.x), aA.x); aA.y = fmaf(w, bf2f(v.y), aA.y);
            aA.z = fmaf(w, bf2f(v.z), aA.z); aA.w = fmaf(w, bf2f(v.w), aA.w);
        }
        {
            const int idx = base + i0 + 8 + slot;
            const float w = bf2f(w_sorted[idx]);
            const ushort4 v = nh4[(size_t)src_sorted[idx] * 32 + lane];
            aB.x = fmaf(w, bf2f(v.x), aB.x); aB.y = fmaf(w, bf2f(v.y), aB.y);
            aB.z = fmaf(w, bf2f(v.z), aB.z); aB.w = fmaf(w, bf2f(v.w), aB.w);
        }
        {
            const int idx = base + i0 + 16 + slot;
            const float w = bf2f(w_sorted[idx]);
            const ushort4 v = nh4[(size_t)src_sorted[idx] * 32 + lane];
            aC.x = fmaf(w, bf2f(v.x), aC.x); aC.y = fmaf(w, bf2f(v.y), aC.y);
            aC.z = fmaf(w, bf2f(v.z), aC.z); aC.w = fmaf(w, bf2f(v.w), aC.w);
        }
        {
            const int idx = base + i0 + 24 + slot;
            const float w = bf2f(w_sorted[idx]);
            const ushort4 v = nh4[(size_t)src_sorted[idx] * 32 + lane];
            aD.x = fmaf(w, bf2f(v.x), aD.x); aD.y = fmaf(w, bf2f(v.y), aD.y);
            aD.z = fmaf(w, bf2f(v.z), aD.z); aD.w = fmaf(w, bf2f(v.w), aD.w);
        }
    }
    for (; i0 < n; i0 += 8) {
        if (i0 + slot < n) {
            const int idx = base + i0 + slot;
            const float w = bf2f(w_sorted[idx]);
            const ushort4 v = nh4[(size_t)src_sorted[idx] * 32 + lane];
            aA.x = fmaf(w, bf2f(v.x), aA.x); aA.y = fmaf(w, bf2f(v.y), aA.y);
            aA.z = fmaf(w, bf2f(v.z), aA.z); aA.w = fmaf(w, bf2f(v.w), aA.w);
        }
    }
    __shared__ float4 red[256];
    red[t] = make_float4((aA.x + aB.x) + (aC.x + aD.x), (aA.y + aB.y) + (aC.y + aD.y),
                         (aA.z + aB.z) + (aC.z + aD.z), (aA.w + aB.w) + (aC.w + aD.w));
    __syncthreads();
    if (t < 32) {
        float4 r = red[t];
#pragma unroll
        for (int k2 = 1; k2 < 8; ++k2) {
            const float4 o = red[t + 32 * k2];
            r.x += o.x; r.y += o.y; r.z += o.z; r.w += o.w;
        }
        ((float4*)(out_sn + (size_t)c * 128))[t] = r;
    }
}

// ---------------- supernode fp32-nodes fallback (ws too small) ----------------
__global__ __launch_bounds__(256) void k_supernode(const int* __restrict__ src_sorted,
                                                   const ushort_t* __restrict__ w_sorted,
                                                   const int* __restrict__ offs, const int* __restrict__ hist,
                                                   const float* __restrict__ nodes, float* __restrict__ out_sn) {
    const int c = blockIdx.x, t = threadIdx.x;
    const int base = offs[c], n = hist[c];
    const int slot = t >> 5, lane = t & 31;
    const float4* nodes4 = (const float4*)nodes;
    float4 aA = make_float4(0.f, 0.f, 0.f, 0.f);
    int i0 = 0;
    for (; i0 < n; i0 += 8) {
        if (i0 + slot < n) {
            const int idx = base + i0 + slot;
            const float w = bf2f(w_sorted[idx]);
            const float4 v = nodes4[(size_t)src_sorted[idx] * 32 + lane];
            aA.x = fmaf(w, v.x, aA.x); aA.y = fmaf(w, v.y, aA.y);
            aA.z = fmaf(w, v.z, aA.z); aA.w = fmaf(w, v.w, aA.w);
        }
    }
    __shared__ float4 red[256];
    red[t] = aA;
    __syncthreads();
    if (t < 32) {
        float4 r = red[t];
#pragma unroll
        for (int k2 = 1; k2 < 8; ++k2) {
            const float4 o = red[t + 32 * k2];
            r.x += o.x; r.y += o.y; r.z += o.z; r.w += o.w;
        }
        ((float4*)(out_sn + (size_t)c * 128))[t] = r;
    }
}

// ---------------- supergraph attention ----------------
__global__ __launch_bounds__(256) void k_sup_dot(const int* __restrict__ ss, const int* __restrict__ sd,
                                                 const float* __restrict__ means, float* __restrict__ satt,
                                                 unsigned* __restrict__ smax, unsigned* __restrict__ smin) {
    const int e = blockIdx.x * 256 + threadIdx.x;
    if (e >= ESN) return;
    const int s = ss[e], d = sd[e];
    const float4* av = (const float4*)(means + (size_t)s * 16);
    const float4* bv = (const float4*)(means + (size_t)d * 16);
    float dot = 0.f;
#pragma unroll
    for (int q = 0; q < 4; ++q) {
        const float4 a = av[q], b = bv[q];
        dot += a.x * b.x + a.y * b.y + a.z * b.z + a.w * b.w;
    }
    satt[e] = dot;
    const unsigned enc = fenc(dot);
    atomicMax(&smax[d], enc);
    atomicMin(&smin[d], enc);
}

__global__ __launch_bounds__(256) void k_sup_tanh(const int* __restrict__ sd, float* __restrict__ satt,
                                                  const unsigned* __restrict__ smax,
                                                  const unsigned* __restrict__ smin) {
    const int e = blockIdx.x * 256 + threadIdx.x;
    if (e >= ESN) return;
    const int d = sd[e];
    const float mx = fdec(smax[d]), mn = fdec(smin[d]);
    satt[e] = tanhf(2.f * (satt[e] - mn) / (EPSA + (mx - mn)));
}

// ---------------- superedge encoder (bf16 MFMA): [32 edges/block] ----------------
__global__ __launch_bounds__(256) void k_edge_mlp(
    const int* __restrict__ esv, const int* __restrict__ edv, const float* __restrict__ sn,
    const ushort_t* __restrict__ W1t, const float* __restrict__ b1, const float* __restrict__ g1,
    const float* __restrict__ be1, const ushort_t* __restrict__ W2t, const float* __restrict__ b2,
    const float* __restrict__ g2, const float* __restrict__ be2, float* __restrict__ out_se) {
    __shared__ ushort_t Xe[32 * 256];   // 16 KB, swizzled
    __shared__ ushort_t Hb[32 * 512];   // 32 KB, swizzled
    __shared__ float redS[4][32], redQ[4][32];
    const int tid = threadIdx.x;
    const int e0 = blockIdx.x * 32;

#pragma unroll
    for (int i = 0; i < 4; ++i) {
        const int c = tid + 256 * i;
        const int row = c >> 5, c8 = c & 31;
        const int node = (c8 < 16) ? esv[e0 + row] : edv[e0 + row];
        const float4* gp = (const float4*)(sn + (size_t)node * 128 + (c8 & 15) * 8);
        const float4 u = gp[0], v = gp[1];
        uint4 pk;
        pk.x = f2bf(u.x) | (f2bf(u.y) << 16);
        pk.y = f2bf(u.z) | (f2bf(u.w) << 16);
        pk.z = f2bf(v.x) | (f2bf(v.y) << 16);
        pk.w = f2bf(v.z) | (f2bf(v.w) << 16);
        const int byte = row * 512 + ((c8 * 16) ^ ((row & 7) << 4));
        *(uint4*)((char*)Xe + byte) = pk;
    }
    __syncthreads();

    const int wv = tid >> 6, l = tid & 63;
    const int q = l >> 4, c16 = l & 15;
    const int wcol0 = wv * 128;

    f32x4 acc[2][8];
#pragma unroll
    for (int mt = 0; mt < 2; ++mt)
#pragma unroll
        for (int nt = 0; nt < 8; ++nt) acc[mt][nt] = (f32x4){0.f, 0.f, 0.f, 0.f};

#pragma unroll
    for (int ks = 0; ks < 8; ++ks) {
        bf16x8 af[2];
#pragma unroll
        for (int mt = 0; mt < 2; ++mt) {
            const int row = 16 * mt + c16;
            const int byte = row * 512 + ((64 * ks + 16 * q) ^ ((row & 7) << 4));
            af[mt] = __builtin_bit_cast(bf16x8, *(const uint4*)((const char*)Xe + byte));
        }
#pragma unroll
        for (int nt = 0; nt < 8; ++nt) {
            const int n = wcol0 + 16 * nt + c16;
            const bf16x8 bfr = __builtin_bit_cast(bf16x8, *(const uint4*)(W1t + n * 256 + 32 * ks + 8 * q));
#pragma unroll
            for (int mt = 0; mt < 2; ++mt)
                acc[mt][nt] = __builtin_amdgcn_mfma_f32_16x16x32_bf16(af[mt], bfr, acc[mt][nt], 0, 0, 0);
        }
    }

    float b1v[8], g1v[8], bev[8];
#pragma unroll
    for (int nt = 0; nt < 8; ++nt) {
        const int col = wcol0 + 16 * nt + c16;
        b1v[nt] = b1[col]; g1v[nt] = g1[col]; bev[nt] = be1[col];
    }
    float sS[2][4], sQ[2][4];
#pragma unroll
    for (int mt = 0; mt < 2; ++mt)
#pragma unroll
        for (int r = 0; r < 4; ++r) {
            float s = 0.f, qq = 0.f;
#pragma unroll
            for (int nt = 0; nt < 8; ++nt) {
                const float h = acc[mt][nt][r] + b1v[nt];
                acc[mt][nt][r] = h;
                s += h; qq += h * h;
            }
#pragma unroll
            for (int off = 1; off < 16; off <<= 1) {
                s += __shfl_xor(s, off);
                qq += __shfl_xor(qq, off);
            }
            sS[mt][r] = s; sQ[mt][r] = qq;
        }
    if (c16 == 0) {
#pragma unroll
        for (int mt = 0; mt < 2; ++mt)
#pragma unroll
            for (int r = 0; r < 4; ++r) {
                const int row = 16 * mt + 4 * q + r;
                redS[wv][row] = sS[mt][r];
                redQ[wv][row] = sQ[mt][r];
            }
    }
    __syncthreads();
#pragma unroll
    for (int mt = 0; mt < 2; ++mt)
#pragma unroll
        for (int r = 0; r < 4; ++r) {
            const int row = 16 * mt + 4 * q + r;
            const float S = redS[0][row] + redS[1][row] + redS[2][row] + redS[3][row];
            const float Q = redQ[0][row] + redQ[1][row] + redQ[2][row] + redQ[3][row];
            const float m_ = S * (1.f / 512.f);
            const float iv = rsqrtf(Q * (1.f / 512.f) - m_ * m_ + 1e-5f);
#pragma unroll
            for (int nt = 0; nt < 8; ++nt) {
                const int col = wcol0 + 16 * nt + c16;
                const float rv = fmaxf((acc[mt][nt][r] - m_) * iv * g1v[nt] + bev[nt], 0.f);
                const int byte = row * 1024 + ((col * 2) ^ ((row & 7) << 4));
                *(ushort_t*)((char*)Hb + byte) = (ushort_t)f2bf(rv);
            }
        }
    __syncthreads();

    f32x4 acc2[2][2];
#pragma unroll
    for (int mt = 0; mt < 2; ++mt)
#pragma unroll
        for (int nt = 0; nt < 2; ++nt) acc2[mt][nt] = (f32x4){0.f, 0.f, 0.f, 0.f};
#pragma unroll 4
    for (int ks = 0; ks < 16; ++ks) {
        bf16x8 bfb[2];
#pragma unroll
        for (int nt = 0; nt < 2; ++nt) {
            const int n = wv * 32 + 16 * nt + c16;
            bfb[nt] = __builtin_bit_cast(bf16x8, *(const uint4*)(W2t + n * 512 + 32 * ks + 8 * q));
        }
#pragma unroll
        for (int mt = 0; mt < 2; ++mt) {
            const int row = 16 * mt + c16;
            const int byte = row * 1024 + ((64 * ks + 16 * q) ^ ((row & 7) << 4));
            const bf16x8 ha = __builtin_bit_cast(bf16x8, *(const uint4*)((const char*)Hb + byte));
#pragma unroll
            for (int nt = 0; nt < 2; ++nt)
                acc2[mt][nt] = __builtin_amdgcn_mfma_f32_16x16x32_bf16(ha, bfb[nt], acc2[mt][nt], 0, 0, 0);
        }
    }

    float b2v[2], g2v[2], be2v[2];
#pragma unroll
    for (int nt = 0; nt < 2; ++nt) {
        const int col = wv * 32 + 16 * nt + c16;
        b2v[nt] = b2[col]; g2v[nt] = g2[col]; be2v[nt] = be2[col];
    }
    float sS2[2][4], sQ2[2][4];
#pragma unroll
    for (int mt = 0; mt < 2; ++mt)
#pragma unroll
        for (int r = 0; r < 4; ++r) {
            float s = 0.f, qq = 0.f;
#pragma unroll
            for (int nt = 0; nt < 2; ++nt) {
                const float h = acc2[mt][nt][r] + b2v[nt];
                acc2[mt][nt][r] = h;
                s += h; qq += h * h;
            }
#pragma unroll
            for (int off = 1; off < 16; off <<= 1) {
                s += __shfl_xor(s, off);
                qq += __shfl_xor(qq, off);
            }
            sS2[mt][r] = s; sQ2[mt][r] = qq;
        }
    __syncthreads();
    if (c16 == 0) {
#pragma unroll
        for (int mt = 0; mt < 2; ++mt)
#pragma unroll
            for (int r = 0; r < 4; ++r) {
                const int row = 16 * mt + 4 * q + r;
                redS[wv][row] = sS2[mt][r];
                redQ[wv][row] = sQ2[mt][r];
            }
    }
    __syncthreads();
#pragma unroll
    for (int mt = 0; mt < 2; ++mt)
#pragma unroll
        for (int r = 0; r < 4; ++r) {
            const int row = 16 * mt + 4 * q + r;
            const float S = redS[0][row] + redS[1][row] + redS[2][row] + redS[3][row];
            const float Q = redQ[0][row] + redQ[1][row] + redQ[2][row] + redQ[3][row];
            const float m_ = S * (1.f / 128.f);
            const float iv = rsqrtf(Q * (1.f / 128.f) - m_ * m_ + 1e-5f);
#pragma unroll
            for (int nt = 0; nt < 2; ++nt) {
                const int col = wv * 32 + 16 * nt + c16;
                const float o = fmaxf((acc2[mt][nt][r] - m_) * iv * g2v[nt] + be2v[nt], 0.f);
                out_se[(size_t)(e0 + row) * 128 + col] = o;
            }
        }
}

extern "C" void kernel_launch(void* const* d_in, const int* in_sizes, int n_in,
                              void* d_out, int out_size, void* d_ws, size_t ws_size,
                              hipStream_t stream) {
    const float* nodes = (const float*)d_in[0];
    const int* clusters = (const int*)d_in[1];
    const int* bsrc = (const int*)d_in[2];
    const int* bdst = (const int*)d_in[3];
    const int* susrc = (const int*)d_in[4];
    const int* sudst = (const int*)d_in[5];
    const float* cW1 = (const float*)d_in[6];
    const float* cb1 = (const float*)d_in[7];
    const float* cg1 = (const float*)d_in[8];
    const float* cbe1 = (const float*)d_in[9];
    const float* cW2 = (const float*)d_in[10];
    const float* cb2 = (const float*)d_in[11];
    const float* eW1 = (const float*)d_in[12];
    const float* eb1 = (const float*)d_in[13];
    const float* eg1 = (const float*)d_in[14];
    const float* ebe1 = (const float*)d_in[15];
    const float* eW2 = (const float*)d_in[16];
    const float* eb2 = (const float*)d_in[17];
    const float* eg2 = (const float*)d_in[18];
    const float* ebe2 = (const float*)d_in[19];

    float* out_sn = (float*)d_out;
    float* out_se = out_sn + (size_t)CC * 128;
    float* out_bip = out_se + (size_t)ESN * 128;
    float* out_satt = out_bip + EBN;

    // workspace layout (u32 units)
    float* sums = (float*)d_ws;                            // 32000
    float* cnt = sums + 32000;                             // 2000
    int* hist_d = (int*)(cnt + 2000);                      // 2000
    int* hist_s = hist_d + 2000;                           // 2000 (NBKT used)
    unsigned* smax = (unsigned*)(hist_s + 2000);           // 2000
    unsigned* smin = smax + 2000;                          // 2000
    ushort_t* emb_h = (ushort_t*)(smin + 2000);            // 3200000 ushort (1.6M u32)
    float* means = (float*)(emb_h + 3200000);              // 32000
    int* offs_d = (int*)(means + 32000);                   // 2000
    int* cursor_d = offs_d + 2000;                         // 2000
    int* offs_s = cursor_d + 2000;                         // 2000
    int* cursor_s = offs_s + 2000;                         // 2000
    int* src_sorted = cursor_s + 2000;                     // 2000000 (overlaid: eid_s before pass C)
    ushort_t* w_sorted = (ushort_t*)(src_sorted + 2000000);// 2000000 ushort (1M u32)
    ushort_t* cW1h = w_sorted + 2000000;                   // 65536 fp16
    ushort_t* cW1pad = cW1h + 512 * 128;                   // 65536 (pad)
    ushort_t* cW2h = cW1pad + 512 * 128;                   // 8192 fp16
    ushort_t* cW2pad = cW2h + 16 * 512;                    // 8192 (pad)
    ushort_t* eW1t = cW2pad + 16 * 512;                    // 131072
    ushort_t* eW2t = eW1t + 512 * 256;                     // 65536
    ushort_t* nodes_h = eW2t + 512 * 128;                  // 25600000 bf16 (51.2 MB)
    unsigned* eid_s = (unsigned*)src_sorted;               // alias: dead before src_sorted written

    const size_t need_bytes = ((size_t)(char*)(nodes_h + (size_t)NN * 128) - (size_t)(char*)d_ws);
    const bool use_nh = ws_size >= need_bytes;

    // init: [sums|cnt|hist_d|hist_s|smax] = 0 ; smin = 0xFF
    hipMemsetAsync(sums, 0, (size_t)(32000 + 2000 + 2000 + 2000 + 2000) * 4, stream);
    hipMemsetAsync(smin, 0xFF, (size_t)2000 * 4, stream);

    k_setup<<<CVB + HSB, 256, 0, stream>>>(cW1, cW2, eW1, eW2, cW1h, cW2h, eW1t, eW2t,
                                           bsrc, bdst, hist_d, hist_s);
    k_scan2<<<2, 1024, 0, stream>>>(hist_d, offs_d, cursor_d, hist_s, offs_s, cursor_s);
    k_mlp1<<<NN / 32, 256, 0, stream>>>(nodes, clusters, cW1h, cb1, cg1, cbe1, cW2h, cb2,
                                        emb_h, sums, cnt, use_nh ? nodes_h : (ushort_t*)nullptr);
    k_means<<<(CC * 16) / 256, 256, 0, stream>>>(sums, cnt, means);
    k_bip_sort<<<EBN / SCH, 512, 0, stream>>>(bsrc, cursor_s, eid_s);
    k_bip_seg<<<NBKT, 512, 0, stream>>>(eid_s, offs_s, hist_s, bdst, emb_h, means, out_bip);
    k_bip_scatter<<<EBN / SCH, 512, 0, stream>>>(bsrc, bdst, out_bip, cursor_d, src_sorted, w_sorted);
    if (use_nh)
        k_supernode_h<<<CC, 256, 0, stream>>>(src_sorted, w_sorted, offs_d, hist_d, nodes_h, out_sn);
    else
        k_supernode<<<CC, 256, 0, stream>>>(src_sorted, w_sorted, offs_d, hist_d, nodes, out_sn);
    k_sup_dot<<<(ESN + 255) / 256, 256, 0, stream>>>(susrc, sudst, means, out_satt, smax, smin);
    k_sup_tanh<<<(ESN + 255) / 256, 256, 0, stream>>>(sudst, out_satt, smax, smin);
    k_edge_mlp<<<ESN / 32, 256, 0, stream>>>(susrc, sudst, out_sn, eW1t, eb1, eg1, ebe1, eW2t, eb2, eg2, ebe2, out_se);
}